// Round 11
// baseline (236.080 us; speedup 1.0000x reference)
//
#include <hip/hip_runtime.h>

#define BATCH  32768
#define ADIM   16
#define HDIM   256
#define DDIM   128
#define KCODES 2048
#define MROWS  64    // batch rows per block
#define SA     264   // LDS row stride in u16 (256 cols + 8 pad; 528 B, 16B-aligned)

typedef unsigned short u16;
typedef short s16x8 __attribute__((ext_vector_type(8)));   // 8 x bf16 bits (MFMA frag)
typedef u16   u16x8 __attribute__((ext_vector_type(8)));
typedef u16   u16x4 __attribute__((ext_vector_type(4)));
typedef float f32x4 __attribute__((ext_vector_type(4)));   // subscriptable, no addr-taking

__device__ __forceinline__ float b2f(u16 u) {
    return __uint_as_float(((unsigned)u) << 16);
}
__device__ __forceinline__ u16 f2b(float f) {            // software RNE (prep only)
    unsigned u = __float_as_uint(f);
    u += 0x7fffu + ((u >> 16) & 1u);
    return (u16)(u >> 16);
}
__device__ __forceinline__ u16 f2bn(float f) {           // native cvt (hot path)
    return __builtin_bit_cast(u16, (__bf16)f);
}
__device__ __forceinline__ float tanh_fast(float x) {    // 1 - 2/(e^2x+1), err ~1e-6
    const float e = __expf(2.f * x);
    return fmaf(-2.f, __builtin_amdgcn_rcpf(e + 1.f), 1.f);
}
__device__ __forceinline__ s16x8 ldb8(const u16* p) {
    return *reinterpret_cast<const s16x8*>(p);
}
__device__ __forceinline__ f32x4 ldf4(const float* p) {
    return *reinterpret_cast<const f32x4*>(p);
}
__device__ __forceinline__ s16x8 ldT(const u16* __restrict__ Wp, int T, int lane) {
    return ldb8(Wp + (T << 9) + lane * 8);   // packed tile T, 16B/lane coalesced
}

// Swapped-operand GEMM: A-operand = packed weight tiles, B-operand = activation rows (LDS).
// acc[i][j]: D[m = wtile j, quad*4+r][n = act row i*16+lrow].
template<int NT, int KC, int PRE>
__device__ __forceinline__ void gemm_pre(const u16* __restrict__ A,
                                         const u16* __restrict__ Wp, int KT, int jn0,
                                         const s16x8* __restrict__ preB,
                                         int lane, int lrow, int kq, f32x4 (&acc)[4][NT])
{
    #pragma unroll
    for (int kc = 0; kc < KC; ++kc) {
        s16x8 a[4], b[NT];
        #pragma unroll
        for (int i = 0; i < 4; ++i) a[i] = ldb8(A + (i * 16 + lrow) * SA + kc * 32 + kq);
        #pragma unroll
        for (int j = 0; j < NT; ++j)
            b[j] = (kc < PRE) ? preB[j * PRE + kc] : ldT(Wp, (jn0 + j) * KT + kc, lane);
        #pragma unroll
        for (int i = 0; i < 4; ++i)
            #pragma unroll
            for (int j = 0; j < NT; ++j)
                acc[i][j] = __builtin_amdgcn_mfma_f32_16x16x32_bf16(b[j], a[i], acc[i][j], 0, 0, 0);
    }
}

// Swapped epilogue: lane holds 4 consecutive out-cols (quad*4+r) of act-row i*16+lrow
// -> packed b64 LDS store; bias read is a coalesced 16B vector (register-subscripted).
template<int NT>
__device__ __forceinline__ void epilogue_st(u16* __restrict__ out,
                                            const float* __restrict__ bias, int n0,
                                            int lrow, int quad, bool relu, f32x4 (&acc)[4][NT])
{
    #pragma unroll
    for (int j = 0; j < NT; ++j) {
        const f32x4 bv = ldf4(bias + n0 + j * 16 + quad * 4);
        #pragma unroll
        for (int i = 0; i < 4; ++i) {
            u16x4 o;
            #pragma unroll
            for (int r = 0; r < 4; ++r) {
                float v = acc[i][j][r] + bv[r];
                if (relu) v = fmaxf(v, 0.f);
                o[r] = f2bn(v);
            }
            *reinterpret_cast<u16x4*>(out + (i * 16 + lrow) * SA + n0 + j * 16 + quad * 4) = o;
        }
    }
}

// ---------------- prep: fragment-pack all weights + E to bf16, E row norms, zero sums.
// packed[(T<<9)+lane*8+t] = W[(j*16+lane%16)*K + kc*32 + (lane/16)*8 + t], T=j*KT+kc.
// Blocks: We2[0,32) We3[32,48) Wd1[48,64) Wd2[64,96) Wh[96,98) We1[98,102) E[102,230)
__global__ __launch_bounds__(256) void vqvae_prep(
    const float* __restrict__ Ef,   const float* __restrict__ We1f,
    const float* __restrict__ We2f, const float* __restrict__ We3f,
    const float* __restrict__ Wd1f, const float* __restrict__ Wd2f,
    const float* __restrict__ Whf,
    u16* __restrict__ Ep,   u16* __restrict__ We1p,
    u16* __restrict__ We2p, u16* __restrict__ We3p,
    u16* __restrict__ Wd1p, u16* __restrict__ Wd2p,
    u16* __restrict__ Whp,  float* __restrict__ ws)
{
    __shared__ float ep[4][16];
    const int b = blockIdx.x, tid = threadIdx.x;
    const int lane = tid & 63, wv = tid >> 6;
    const int lrow = lane & 15, quad = lane >> 4;

    if (b == 0 && tid < 3) {
        if (tid == 2) reinterpret_cast<unsigned*>(ws)[2] = 0u;
        else ws[tid] = 0.f;
    }

    if (b < 98) {
        const float* src; u16* dst; int KT, Tb;
        if      (b < 32) { src = We2f; dst = We2p; KT = 8; Tb = b * 4; }
        else if (b < 48) { src = We3f; dst = We3p; KT = 8; Tb = (b - 32) * 4; }
        else if (b < 64) { src = Wd1f; dst = Wd1p; KT = 4; Tb = (b - 48) * 4; }
        else if (b < 96) { src = Wd2f; dst = Wd2p; KT = 8; Tb = (b - 64) * 4; }
        else             { src = Whf;  dst = Whp;  KT = 8; Tb = (b - 96) * 4; }
        const int T = Tb + wv;
        const int j = T / KT, kc = T % KT;
        const float* p = src + (j * 16 + lrow) * (KT * 32) + kc * 32 + quad * 8;
        const f32x4 v0 = ldf4(p);
        const f32x4 v1 = ldf4(p + 4);
        u16x8 o;
        #pragma unroll
        for (int t = 0; t < 4; ++t) { o[t] = f2b(v0[t]); o[4 + t] = f2b(v1[t]); }
        *reinterpret_cast<u16x8*>(dst + (T << 9) + lane * 8) = o;
    } else if (b < 102) {
        // We1 (256x16), K zero-padded to 32: KT=1, tile=j.
        const int T = (b - 98) * 4 + wv;
        u16x8 o = {0, 0, 0, 0, 0, 0, 0, 0};
        if (quad < 2) {
            const float* p = We1f + (T * 16 + lrow) * ADIM + quad * 8;
            const f32x4 v0 = ldf4(p);
            const f32x4 v1 = ldf4(p + 4);
            #pragma unroll
            for (int t = 0; t < 4; ++t) { o[t] = f2b(v0[t]); o[4 + t] = f2b(v1[t]); }
        }
        *reinterpret_cast<u16x8*>(We1p + (T << 9) + lane * 8) = o;
    } else {
        // E (2048x128): KT=4; block covers one 16-code group jb, kc = wv. Also |e|^2.
        const int jb = b - 102;
        const int T = jb * 4 + wv;
        const float* p = Ef + (jb * 16 + lrow) * DDIM + wv * 32 + quad * 8;
        const f32x4 v0 = ldf4(p);
        const f32x4 v1 = ldf4(p + 4);
        u16x8 o;
        #pragma unroll
        for (int t = 0; t < 4; ++t) { o[t] = f2b(v0[t]); o[4 + t] = f2b(v1[t]); }
        *reinterpret_cast<u16x8*>(Ep + (T << 9) + lane * 8) = o;
        float s = 0.f;
        #pragma unroll
        for (int t = 0; t < 8; ++t) { const float f = b2f(o[t]); s += f * f; }
        s += __shfl_xor(s, 16, 64);
        s += __shfl_xor(s, 32, 64);
        if (lane < 16) ep[wv][lane] = s;
        __syncthreads();
        if (tid < 16) ws[4 + jb * 16 + tid] = ep[0][tid] + ep[1][tid] + ep[2][tid] + ep[3][tid];
    }
}

// ---------------- main fused kernel: round-8 structure + swapped MFMA operands,
// packed b64 epilogues, native bf16 cvt, fast tanh, lean S4 argmin. No addr-taken vectors.
__global__ __launch_bounds__(512) void ActionVQVAE_49452253446164_kernel(
    const float* __restrict__ action,
    const u16* __restrict__ We1p, const float* __restrict__ be1,
    const u16* __restrict__ We2p, const float* __restrict__ be2,
    const u16* __restrict__ We3p, const float* __restrict__ be3,
    const u16* __restrict__ Ep,   const float* __restrict__ enorms,
    const u16* __restrict__ Wd1p, const float* __restrict__ bd1,
    const u16* __restrict__ Wd2p, const float* __restrict__ bd2,
    const u16* __restrict__ Whp,  const float* __restrict__ bh,
    float* __restrict__ sums, unsigned* __restrict__ counter, float* __restrict__ out)
{
    // buf: h1 -> h2 -> [enc cols 0..127 | q cols 128..255] -> d1 -> d2 (in-place)
    __shared__ u16   buf[MROWS * SA];
    __shared__ float red_val[8][MROWS];
    __shared__ int   red_idx[8][MROWS];
    __shared__ int   qidx[MROWS];
    __shared__ float wsum[16];

    const int tid  = threadIdx.x;
    const int wave = tid >> 6;
    const int lane = tid & 63;
    const int lrow = lane & 15;
    const int quad = lane >> 4;
    const int kq   = quad * 8;
    const int base = blockIdx.x * MROWS;

    float vq_acc = 0.f, rec_acc = 0.f;
    s16x8 preB[8];   // cross-barrier prefetch staging (weight/E A-operand tiles)

    // ---------- S1: h1 = relu(action @ We1^T + be1) -> buf   (K=16 zero-padded; NT=2)
    {
        s16x8 b1[2];
        #pragma unroll
        for (int j = 0; j < 2; ++j) b1[j] = ldT(We1p, wave * 2 + j, lane);
        f32x4 acc[4][2];
        #pragma unroll
        for (int i = 0; i < 4; ++i)
            #pragma unroll
            for (int j = 0; j < 2; ++j) { f32x4 z = {0.f, 0.f, 0.f, 0.f}; acc[i][j] = z; }
        s16x8 a[4];
        s16x8 zf = {0, 0, 0, 0, 0, 0, 0, 0};
        #pragma unroll
        for (int i = 0; i < 4; ++i) a[i] = zf;
        if (quad < 2) {
            #pragma unroll
            for (int i = 0; i < 4; ++i) {
                const float* p = action + (base + i * 16 + lrow) * ADIM + kq;
                const f32x4 v0 = ldf4(p);
                const f32x4 v1 = ldf4(p + 4);
                s16x8 f;
                #pragma unroll
                for (int t = 0; t < 4; ++t) {
                    f[t]     = (short)f2bn(v0[t]);
                    f[4 + t] = (short)f2bn(v1[t]);
                }
                a[i] = f;
            }
        }
        #pragma unroll
        for (int i = 0; i < 4; ++i)
            #pragma unroll
            for (int j = 0; j < 2; ++j)
                acc[i][j] = __builtin_amdgcn_mfma_f32_16x16x32_bf16(b1[j], a[i], acc[i][j], 0, 0, 0);
        // prefetch S2 first 4 kc-slices (j=2 x kc=4)
        #pragma unroll
        for (int j = 0; j < 2; ++j)
            #pragma unroll
            for (int kc = 0; kc < 4; ++kc)
                preB[j * 4 + kc] = ldT(We2p, (wave * 2 + j) * 8 + kc, lane);
        epilogue_st<2>(buf, be1, wave * 32, lrow, quad, true, acc);
    }
    __syncthreads();

    // ---------- S2: h2 = relu(h1 @ We2^T + be2), in place   (NT=2, KC=8, PRE=4)
    {
        f32x4 acc[4][2];
        #pragma unroll
        for (int i = 0; i < 4; ++i)
            #pragma unroll
            for (int j = 0; j < 2; ++j) { f32x4 z = {0.f, 0.f, 0.f, 0.f}; acc[i][j] = z; }
        gemm_pre<2, 8, 4>(buf, We2p, 8, wave * 2, preB, lane, lrow, kq, acc);
        // prefetch S3 first 4 kc-slices (NT=1)
        #pragma unroll
        for (int kc = 0; kc < 4; ++kc) preB[kc] = ldT(We3p, wave * 8 + kc, lane);
        __syncthreads();                       // all waves done reading h1
        epilogue_st<2>(buf, be2, wave * 32, lrow, quad, true, acc);
    }
    __syncthreads();

    // ---------- S3: enc = h2 @ We3^T + be3 -> buf cols 0..127   (NT=1, KC=8, PRE=4)
    {
        f32x4 acc[4][1];
        #pragma unroll
        for (int i = 0; i < 4; ++i) { f32x4 z = {0.f, 0.f, 0.f, 0.f}; acc[i][0] = z; }
        gemm_pre<1, 8, 4>(buf, We3p, 8, wave, preB, lane, lrow, kq, acc);
        // prefetch S4 chunk0 kc0..1 (j=4 x kc=2)
        #pragma unroll
        for (int j = 0; j < 4; ++j)
            #pragma unroll
            for (int kc = 0; kc < 2; ++kc)
                preB[j * 2 + kc] = ldT(Ep, (wave * 16 + j) * 4 + kc, lane);
        __syncthreads();                       // all waves done reading h2
        epilogue_st<1>(buf, be3, wave * 16, lrow, quad, false, acc);
    }
    __syncthreads();

    // ---------- S4: argmin_k |e_k|^2 - 2*enc.e_k; wave sweeps 256 codes (16 tiles).
    // Swapped: D[m=code quad*4+r][n=row i*16+lrow] -> per-lane state is 4 row-slots.
    {
        s16x8 afr[4][4];                       // enc fragments [kc][i], hoisted once
        #pragma unroll
        for (int kc = 0; kc < 4; ++kc) {
            #pragma unroll
            for (int i = 0; i < 4; ++i)
                afr[kc][i] = ldb8(buf + (i * 16 + lrow) * SA + kc * 32 + kq);
        }
        float minv[4]; int mini[4];
        #pragma unroll
        for (int s = 0; s < 4; ++s) { minv[s] = 3.4e38f; mini[s] = 0; }

        #pragma unroll
        for (int c = 0; c < 4; ++c) {
            const int tb = wave * 16 + c * 4;
            f32x4 acc[4][4];
            #pragma unroll
            for (int i = 0; i < 4; ++i)
                #pragma unroll
                for (int j = 0; j < 4; ++j) { f32x4 z = {0.f, 0.f, 0.f, 0.f}; acc[i][j] = z; }
            #pragma unroll
            for (int kc = 0; kc < 4; ++kc) {
                s16x8 b[4];
                #pragma unroll
                for (int j = 0; j < 4; ++j)
                    b[j] = (c == 0 && kc < 2) ? preB[j * 2 + kc]
                                              : ldT(Ep, (tb + j) * 4 + kc, lane);
                #pragma unroll
                for (int i = 0; i < 4; ++i)
                    #pragma unroll
                    for (int j = 0; j < 4; ++j)
                        acc[i][j] = __builtin_amdgcn_mfma_f32_16x16x32_bf16(b[j], afr[kc][i], acc[i][j], 0, 0, 0);
            }
            #pragma unroll
            for (int j = 0; j < 4; ++j) {
                const f32x4 en = ldf4(enorms + (tb + j) * 16 + quad * 4);
                #pragma unroll
                for (int i = 0; i < 4; ++i)
                    #pragma unroll
                    for (int r = 0; r < 4; ++r) {
                        const float d2 = fmaf(-2.f, acc[i][j][r], en[r]);
                        if (d2 < minv[i]) { minv[i] = d2; mini[i] = (tb + j) * 16 + quad * 4 + r; }
                    }
            }
        }
        // combine the 4 quads (lanes sharing lrow): 2 shuffle steps
        #pragma unroll
        for (int off = 16; off < 64; off <<= 1) {
            #pragma unroll
            for (int s = 0; s < 4; ++s) {
                const float ov = __shfl_xor(minv[s], off, 64);
                const int   oi = __shfl_xor(mini[s], off, 64);
                if (ov < minv[s] || (ov == minv[s] && oi < mini[s])) { minv[s] = ov; mini[s] = oi; }
            }
        }
        if (quad == 0) {
            #pragma unroll
            for (int i = 0; i < 4; ++i) {
                red_val[wave][i * 16 + lrow] = minv[i];
                red_idx[wave][i * 16 + lrow] = mini[i];
            }
        }
        // prefetch S6 first 2 kc-slices (j=2 x kc=2) — independent of the reductions
        #pragma unroll
        for (int j = 0; j < 2; ++j)
            #pragma unroll
            for (int kc = 0; kc < 2; ++kc)
                preB[j * 2 + kc] = ldT(Wd1p, (wave * 2 + j) * 4 + kc, lane);
    }
    __syncthreads();
    if (tid < MROWS) {
        float bv = red_val[0][tid]; int bi = red_idx[0][tid];
        #pragma unroll
        for (int w = 1; w < 8; ++w) {
            const float v = red_val[w][tid]; const int ii = red_idx[w][tid];
            if (v < bv || (v == bv && ii < bi)) { bv = v; bi = ii; }
        }
        qidx[tid] = bi;
    }
    __syncthreads();

    // ---------- S5: gather q -> buf cols 128..255 (enc in 0..127 untouched); vq += (enc-q)^2
    {
        const int row  = tid >> 3;             // 64 rows, 8 threads/row
        const int t    = tid & 7;
        const int kc   = t >> 1;
        const int half = t & 1;
        const int code = qidx[row];
        const int T    = (code >> 4) * 4 + kc;
        const u16* eb  = Ep + (T << 9) + (code & 15) * 8;
        #pragma unroll
        for (int h = 0; h < 2; ++h) {
            const int qd  = half * 2 + h;
            const u16x8 qv = *reinterpret_cast<const u16x8*>(eb + qd * 128);
            const int col = kc * 32 + qd * 8;
            const u16x8 ev = *reinterpret_cast<const u16x8*>(buf + row * SA + col);
            *reinterpret_cast<u16x8*>(buf + row * SA + 128 + col) = qv;
            #pragma unroll
            for (int e = 0; e < 8; ++e) {
                const float d = b2f(ev[e]) - b2f(qv[e]);
                vq_acc += d * d;
            }
        }
    }
    __syncthreads();

    // ---------- S6: d1 = relu(q @ Wd1^T + bd1): reads cols 128..255, writes 0..255
    {
        f32x4 acc[4][2];
        #pragma unroll
        for (int i = 0; i < 4; ++i)
            #pragma unroll
            for (int j = 0; j < 2; ++j) { f32x4 z = {0.f, 0.f, 0.f, 0.f}; acc[i][j] = z; }
        gemm_pre<2, 4, 2>(buf + 128, Wd1p, 4, wave * 2, preB, lane, lrow, kq, acc);
        // prefetch S7 first 4 kc-slices (j=2 x kc=4)
        #pragma unroll
        for (int j = 0; j < 2; ++j)
            #pragma unroll
            for (int kc = 0; kc < 4; ++kc)
                preB[j * 4 + kc] = ldT(Wd2p, (wave * 2 + j) * 8 + kc, lane);
        __syncthreads();                       // all waves done reading q
        epilogue_st<2>(buf, bd1, wave * 32, lrow, quad, true, acc);
    }
    __syncthreads();

    // ---------- S7: d2 = relu(d1 @ Wd2^T + bd2), in place   (NT=2, KC=8, PRE=4)
    {
        f32x4 acc[4][2];
        #pragma unroll
        for (int i = 0; i < 4; ++i)
            #pragma unroll
            for (int j = 0; j < 2; ++j) { f32x4 z = {0.f, 0.f, 0.f, 0.f}; acc[i][j] = z; }
        gemm_pre<2, 8, 4>(buf, Wd2p, 8, wave * 2, preB, lane, lrow, kq, acc);
        // prefetch S8 Wh fragments (waves 0..3 only)
        if (wave < 4) {
            #pragma unroll
            for (int kc = 0; kc < 8; ++kc) preB[kc] = ldT(Whp, kc, lane);
        }
        __syncthreads();                       // all waves done reading d1
        epilogue_st<2>(buf, bd2, wave * 32, lrow, quad, true, acc);
    }
    __syncthreads();

    // ---------- S8: recons = tanh(d2 @ Wh^T + bh); rec += (recons - action)^2 (fp32)
    // Swapped: D[m=adim quad*4+r][n=row m0+lrow]; action/bias reads are 16B vectors.
    if (wave < 4) {
        const int m0 = wave * 16;
        f32x4 acc = {0.f, 0.f, 0.f, 0.f};
        #pragma unroll
        for (int kc = 0; kc < 8; ++kc) {
            s16x8 a = ldb8(buf + (m0 + lrow) * SA + kc * 32 + kq);
            acc = __builtin_amdgcn_mfma_f32_16x16x32_bf16(preB[kc], a, acc, 0, 0, 0);
        }
        const f32x4 bh4 = ldf4(bh + quad * 4);
        const f32x4 av4 = ldf4(action + (base + m0 + lrow) * ADIM + quad * 4);
        #pragma unroll
        for (int r = 0; r < 4; ++r) {
            const float v = tanh_fast(acc[r] + bh4[r]);
            const float d = v - av4[r];
            rec_acc += d * d;
        }
    }

    // ---------- block reduction + atomics + last-block finalize
    #pragma unroll
    for (int off = 1; off < 64; off <<= 1) {
        vq_acc  += __shfl_xor(vq_acc,  off, 64);
        rec_acc += __shfl_xor(rec_acc, off, 64);
    }
    if (lane == 0) { wsum[wave] = rec_acc; wsum[8 + wave] = vq_acc; }
    __syncthreads();
    if (tid == 0) {
        float r = 0.f, v = 0.f;
        #pragma unroll
        for (int w = 0; w < 8; ++w) { r += wsum[w]; v += wsum[8 + w]; }
        atomicAdd(&sums[0], r);
        atomicAdd(&sums[1], v);
        __threadfence();
        const unsigned old = atomicAdd(counter, 1u);
        if (old == gridDim.x - 1) {
            const float s0 = atomicAdd(&sums[0], 0.f);
            const float s1 = atomicAdd(&sums[1], 0.f);
            const float recons_loss = s0 / (float)(BATCH * ADIM);
            const float vq_loss     = 1.25f * (s1 / (float)(BATCH * DDIM));
            out[0] = recons_loss + vq_loss;
        }
    }
}

extern "C" void kernel_launch(void* const* d_in, const int* in_sizes, int n_in,
                              void* d_out, int out_size, void* d_ws, size_t ws_size,
                              hipStream_t stream)
{
    const float* action = (const float*)d_in[0];
    const float* We1f = (const float*)d_in[1];
    const float* be1  = (const float*)d_in[2];
    const float* We2f = (const float*)d_in[3];
    const float* be2  = (const float*)d_in[4];
    const float* We3f = (const float*)d_in[5];
    const float* be3  = (const float*)d_in[6];
    const float* Ef   = (const float*)d_in[7];
    const float* Wd1f = (const float*)d_in[8];
    const float* bd1  = (const float*)d_in[9];
    const float* Wd2f = (const float*)d_in[10];
    const float* bd2  = (const float*)d_in[11];
    const float* Whf  = (const float*)d_in[12];
    const float* bh   = (const float*)d_in[13];

    float* ws = (float*)d_ws;          // [0]rec [1]vq [2]counter [3]pad [4..2052)enorms
    u16* wb = (u16*)(ws + 2052);       // packed bf16 area, 16B-aligned
    u16* Ep   = wb;                    // 262144
    u16* We1p = Ep   + KCODES * DDIM;  // 8192 (K padded to 32)
    u16* We2p = We1p + HDIM * 32;      // 65536
    u16* We3p = We2p + HDIM * HDIM;    // 32768
    u16* Wd1p = We3p + DDIM * HDIM;    // 32768
    u16* Wd2p = Wd1p + HDIM * DDIM;    // 65536
    u16* Whp  = Wd2p + HDIM * HDIM;    // 4096

    vqvae_prep<<<230, 256, 0, stream>>>(Ef, We1f, We2f, We3f, Wd1f, Wd2f, Whf,
                                        Ep, We1p, We2p, We3p, Wd1p, Wd2p, Whp, ws);
    ActionVQVAE_49452253446164_kernel<<<BATCH / MROWS, 512, 0, stream>>>(
        action, We1p, be1, We2p, be2, We3p, be3,
        Ep, ws + 4, Wd1p, bd1, Wd2p, bd2, Whp, bh,
        ws, (unsigned*)(ws + 2), (float*)d_out);
}

// Round 12
// 158.111 us; speedup vs baseline: 1.4931x; 1.4931x over previous
//
#include <hip/hip_runtime.h>

#define BATCH  32768
#define ADIM   16
#define HDIM   256
#define DDIM   128
#define KCODES 2048
#define MROWS  64    // batch rows per block
#define SA     264   // LDS row stride in u16 (256 cols + 8 pad; 528 B, 16B-aligned)

typedef unsigned short u16;
typedef short s16x8 __attribute__((ext_vector_type(8)));   // 8 x bf16 bits (MFMA frag)
typedef u16   u16x8 __attribute__((ext_vector_type(8)));
typedef float f32x4 __attribute__((ext_vector_type(4)));

__device__ __forceinline__ float b2f(u16 u) {
    return __uint_as_float(((unsigned)u) << 16);
}
__device__ __forceinline__ u16 f2b(float f) {            // software RNE (prep only)
    unsigned u = __float_as_uint(f);
    u += 0x7fffu + ((u >> 16) & 1u);
    return (u16)(u >> 16);
}
__device__ __forceinline__ u16 f2bn(float f) {           // native cvt (hot path)
    return __builtin_bit_cast(u16, (__bf16)f);
}
__device__ __forceinline__ float tanh_fast(float x) {    // 1 - 2/(e^2x+1), err ~1e-6
    const float e = __expf(2.f * x);
    return fmaf(-2.f, __builtin_amdgcn_rcpf(e + 1.f), 1.f);
}
__device__ __forceinline__ s16x8 ldb8(const u16* p) {
    return *reinterpret_cast<const s16x8*>(p);
}
__device__ __forceinline__ s16x8 ldT(const u16* __restrict__ Wp, int T, int lane) {
    return ldb8(Wp + (T << 9) + lane * 8);   // packed tile T, 16B/lane coalesced
}

// GEMM with PRE preloaded kc-slices: C(64 x NT*16) += A(64xKC*32, LDS) * W^T.
template<int NT, int KC, int PRE>
__device__ __forceinline__ void gemm_pre(const u16* __restrict__ A,
                                         const u16* __restrict__ Wp, int KT, int jn0,
                                         const s16x8* __restrict__ preB,
                                         int lane, int lrow, int kq, f32x4 (&acc)[4][NT])
{
    #pragma unroll
    for (int kc = 0; kc < KC; ++kc) {
        s16x8 a[4], b[NT];
        #pragma unroll
        for (int i = 0; i < 4; ++i) a[i] = ldb8(A + (i * 16 + lrow) * SA + kc * 32 + kq);
        #pragma unroll
        for (int j = 0; j < NT; ++j)
            b[j] = (kc < PRE) ? preB[j * PRE + kc] : ldT(Wp, (jn0 + j) * KT + kc, lane);
        #pragma unroll
        for (int i = 0; i < 4; ++i)
            #pragma unroll
            for (int j = 0; j < NT; ++j)
                acc[i][j] = __builtin_amdgcn_mfma_f32_16x16x32_bf16(a[i], b[j], acc[i][j], 0, 0, 0);
    }
}

// Epilogue: bias + optional relu, store bf16 to LDS. C/D: row=quad*4+r, col=lane&15.
template<int NT>
__device__ __forceinline__ void epilogue_st(u16* __restrict__ out,
                                            const float* __restrict__ bias, int n0,
                                            int lrow, int quad, bool relu, f32x4 (&acc)[4][NT])
{
    #pragma unroll
    for (int j = 0; j < NT; ++j) {
        const float bv = bias[n0 + j * 16 + lrow];
        #pragma unroll
        for (int i = 0; i < 4; ++i)
            #pragma unroll
            for (int r = 0; r < 4; ++r) {
                float v = acc[i][j][r] + bv;
                if (relu) v = fmaxf(v, 0.f);
                out[(i * 16 + quad * 4 + r) * SA + n0 + j * 16 + lrow] = f2bn(v);
            }
    }
}

// ---------------- prep: fragment-pack all weights + E to bf16, E row norms, zero sums.
// packed[(T<<9)+lane*8+t] = W[(j*16+lane%16)*K + kc*32 + (lane/16)*8 + t], T=j*KT+kc.
// Blocks: We2[0,32) We3[32,48) Wd1[48,64) Wd2[64,96) Wh[96,98) We1[98,102) E[102,230)
__global__ __launch_bounds__(256) void vqvae_prep(
    const float* __restrict__ Ef,   const float* __restrict__ We1f,
    const float* __restrict__ We2f, const float* __restrict__ We3f,
    const float* __restrict__ Wd1f, const float* __restrict__ Wd2f,
    const float* __restrict__ Whf,
    u16* __restrict__ Ep,   u16* __restrict__ We1p,
    u16* __restrict__ We2p, u16* __restrict__ We3p,
    u16* __restrict__ Wd1p, u16* __restrict__ Wd2p,
    u16* __restrict__ Whp,  float* __restrict__ ws)
{
    __shared__ float ep[4][16];
    const int b = blockIdx.x, tid = threadIdx.x;
    const int lane = tid & 63, wv = tid >> 6;
    const int lrow = lane & 15, quad = lane >> 4;

    if (b == 0 && tid < 3) {
        if (tid == 2) reinterpret_cast<unsigned*>(ws)[2] = 0u;
        else ws[tid] = 0.f;
    }

    if (b < 98) {
        const float* src; u16* dst; int KT, Tb;
        if      (b < 32) { src = We2f; dst = We2p; KT = 8; Tb = b * 4; }
        else if (b < 48) { src = We3f; dst = We3p; KT = 8; Tb = (b - 32) * 4; }
        else if (b < 64) { src = Wd1f; dst = Wd1p; KT = 4; Tb = (b - 48) * 4; }
        else if (b < 96) { src = Wd2f; dst = Wd2p; KT = 8; Tb = (b - 64) * 4; }
        else             { src = Whf;  dst = Whp;  KT = 8; Tb = (b - 96) * 4; }
        const int T = Tb + wv;
        const int j = T / KT, kc = T % KT;
        const float* p = src + (j * 16 + lrow) * (KT * 32) + kc * 32 + quad * 8;
        const float4 v0 = *reinterpret_cast<const float4*>(p);
        const float4 v1 = *reinterpret_cast<const float4*>(p + 4);
        u16x8 o;
        o[0] = f2b(v0.x); o[1] = f2b(v0.y); o[2] = f2b(v0.z); o[3] = f2b(v0.w);
        o[4] = f2b(v1.x); o[5] = f2b(v1.y); o[6] = f2b(v1.z); o[7] = f2b(v1.w);
        *reinterpret_cast<u16x8*>(dst + (T << 9) + lane * 8) = o;
    } else if (b < 102) {
        // We1 (256x16), K zero-padded to 32: KT=1, tile=j.
        const int T = (b - 98) * 4 + wv;
        u16x8 o = {0, 0, 0, 0, 0, 0, 0, 0};
        if (quad < 2) {
            const float* p = We1f + (T * 16 + lrow) * ADIM + quad * 8;
            const float4 v0 = *reinterpret_cast<const float4*>(p);
            const float4 v1 = *reinterpret_cast<const float4*>(p + 4);
            o[0] = f2b(v0.x); o[1] = f2b(v0.y); o[2] = f2b(v0.z); o[3] = f2b(v0.w);
            o[4] = f2b(v1.x); o[5] = f2b(v1.y); o[6] = f2b(v1.z); o[7] = f2b(v1.w);
        }
        *reinterpret_cast<u16x8*>(We1p + (T << 9) + lane * 8) = o;
    } else {
        // E (2048x128): KT=4; block covers one 16-code group jb, kc = wv. Also |e|^2.
        const int jb = b - 102;
        const int T = jb * 4 + wv;
        const float* p = Ef + (jb * 16 + lrow) * DDIM + wv * 32 + quad * 8;
        const float4 v0 = *reinterpret_cast<const float4*>(p);
        const float4 v1 = *reinterpret_cast<const float4*>(p + 4);
        u16x8 o;
        o[0] = f2b(v0.x); o[1] = f2b(v0.y); o[2] = f2b(v0.z); o[3] = f2b(v0.w);
        o[4] = f2b(v1.x); o[5] = f2b(v1.y); o[6] = f2b(v1.z); o[7] = f2b(v1.w);
        *reinterpret_cast<u16x8*>(Ep + (T << 9) + lane * 8) = o;
        float s = 0.f;
        #pragma unroll
        for (int t = 0; t < 8; ++t) { const float f = b2f(o[t]); s += f * f; }
        s += __shfl_xor(s, 16, 64);
        s += __shfl_xor(s, 32, 64);
        if (lane < 16) ep[wv][lane] = s;
        __syncthreads();
        if (tid < 16) ws[4 + jb * 16 + tid] = ep[0][tid] + ep[1][tid] + ep[2][tid] + ep[3][tid];
    }
}

// ---------------- main fused kernel: round-8 structure (proven 85 µs, no spills) +
// native bf16 cvt + fast tanh. Single in-place LDS buffer, packed W/E, prefetch.
__global__ __launch_bounds__(512) void ActionVQVAE_49452253446164_kernel(
    const float* __restrict__ action,
    const u16* __restrict__ We1p, const float* __restrict__ be1,
    const u16* __restrict__ We2p, const float* __restrict__ be2,
    const u16* __restrict__ We3p, const float* __restrict__ be3,
    const u16* __restrict__ Ep,   const float* __restrict__ enorms,
    const u16* __restrict__ Wd1p, const float* __restrict__ bd1,
    const u16* __restrict__ Wd2p, const float* __restrict__ bd2,
    const u16* __restrict__ Whp,  const float* __restrict__ bh,
    float* __restrict__ sums, unsigned* __restrict__ counter, float* __restrict__ out)
{
    // buf: h1 -> h2 -> [enc cols 0..127 | q cols 128..255] -> d1 -> d2 (in-place)
    __shared__ u16   buf[MROWS * SA];
    __shared__ float red_val[8][MROWS];
    __shared__ int   red_idx[8][MROWS];
    __shared__ int   qidx[MROWS];
    __shared__ float wsum[16];

    const int tid  = threadIdx.x;
    const int wave = tid >> 6;
    const int lane = tid & 63;
    const int lrow = lane & 15;
    const int quad = lane >> 4;
    const int kq   = quad * 8;
    const int base = blockIdx.x * MROWS;

    float vq_acc = 0.f, rec_acc = 0.f;
    s16x8 preB[8];   // cross-barrier prefetch staging

    // ---------- S1: h1 = relu(action @ We1^T + be1) -> buf   (K=16 zero-padded; NT=2)
    {
        s16x8 b1[2];
        #pragma unroll
        for (int j = 0; j < 2; ++j) b1[j] = ldT(We1p, wave * 2 + j, lane);
        f32x4 acc[4][2];
        #pragma unroll
        for (int i = 0; i < 4; ++i)
            #pragma unroll
            for (int j = 0; j < 2; ++j) { f32x4 z = {0.f, 0.f, 0.f, 0.f}; acc[i][j] = z; }
        s16x8 a[4];
        s16x8 zf = {0, 0, 0, 0, 0, 0, 0, 0};
        #pragma unroll
        for (int i = 0; i < 4; ++i) a[i] = zf;
        if (quad < 2) {
            #pragma unroll
            for (int i = 0; i < 4; ++i) {
                const float* p = action + (base + i * 16 + lrow) * ADIM + kq;
                const float4 v0 = *reinterpret_cast<const float4*>(p);
                const float4 v1 = *reinterpret_cast<const float4*>(p + 4);
                s16x8 f;
                f[0] = (short)f2bn(v0.x); f[1] = (short)f2bn(v0.y);
                f[2] = (short)f2bn(v0.z); f[3] = (short)f2bn(v0.w);
                f[4] = (short)f2bn(v1.x); f[5] = (short)f2bn(v1.y);
                f[6] = (short)f2bn(v1.z); f[7] = (short)f2bn(v1.w);
                a[i] = f;
            }
        }
        #pragma unroll
        for (int i = 0; i < 4; ++i)
            #pragma unroll
            for (int j = 0; j < 2; ++j)
                acc[i][j] = __builtin_amdgcn_mfma_f32_16x16x32_bf16(a[i], b1[j], acc[i][j], 0, 0, 0);
        // prefetch S2 first 4 kc-slices (j=2 x kc=4)
        #pragma unroll
        for (int j = 0; j < 2; ++j)
            #pragma unroll
            for (int kc = 0; kc < 4; ++kc)
                preB[j * 4 + kc] = ldT(We2p, (wave * 2 + j) * 8 + kc, lane);
        epilogue_st<2>(buf, be1, wave * 32, lrow, quad, true, acc);
    }
    __syncthreads();

    // ---------- S2: h2 = relu(h1 @ We2^T + be2), in place   (NT=2, KC=8, PRE=4)
    {
        f32x4 acc[4][2];
        #pragma unroll
        for (int i = 0; i < 4; ++i)
            #pragma unroll
            for (int j = 0; j < 2; ++j) { f32x4 z = {0.f, 0.f, 0.f, 0.f}; acc[i][j] = z; }
        gemm_pre<2, 8, 4>(buf, We2p, 8, wave * 2, preB, lane, lrow, kq, acc);
        // prefetch S3 first 4 kc-slices (NT=1)
        #pragma unroll
        for (int kc = 0; kc < 4; ++kc) preB[kc] = ldT(We3p, wave * 8 + kc, lane);
        __syncthreads();                       // all waves done reading h1
        epilogue_st<2>(buf, be2, wave * 32, lrow, quad, true, acc);
    }
    __syncthreads();

    // ---------- S3: enc = h2 @ We3^T + be3 -> buf cols 0..127   (NT=1, KC=8, PRE=4)
    {
        f32x4 acc[4][1];
        #pragma unroll
        for (int i = 0; i < 4; ++i) { f32x4 z = {0.f, 0.f, 0.f, 0.f}; acc[i][0] = z; }
        gemm_pre<1, 8, 4>(buf, We3p, 8, wave, preB, lane, lrow, kq, acc);
        // prefetch S4 chunk0 kc0..1 (j=4 x kc=2)
        #pragma unroll
        for (int j = 0; j < 4; ++j)
            #pragma unroll
            for (int kc = 0; kc < 2; ++kc)
                preB[j * 2 + kc] = ldT(Ep, (wave * 16 + j) * 4 + kc, lane);
        __syncthreads();                       // all waves done reading h2
        epilogue_st<1>(buf, be3, wave * 16, lrow, quad, false, acc);
    }
    __syncthreads();

    // ---------- S4: argmin_k |e_k|^2 - 2*enc.e_k; wave sweeps 256 codes (16 tiles)
    {
        s16x8 afr[4][4];                       // enc fragments [kc][i], hoisted once
        #pragma unroll
        for (int kc = 0; kc < 4; ++kc) {
            #pragma unroll
            for (int i = 0; i < 4; ++i)
                afr[kc][i] = ldb8(buf + (i * 16 + lrow) * SA + kc * 32 + kq);
        }
        float minv[16]; int mini[16];
        #pragma unroll
        for (int s = 0; s < 16; ++s) { minv[s] = 3.4e38f; mini[s] = 0; }

        #pragma unroll
        for (int c = 0; c < 4; ++c) {
            const int tb = wave * 16 + c * 4;
            f32x4 acc[4][4];
            #pragma unroll
            for (int i = 0; i < 4; ++i)
                #pragma unroll
                for (int j = 0; j < 4; ++j) { f32x4 z = {0.f, 0.f, 0.f, 0.f}; acc[i][j] = z; }
            #pragma unroll
            for (int kc = 0; kc < 4; ++kc) {
                s16x8 b[4];
                #pragma unroll
                for (int j = 0; j < 4; ++j)
                    b[j] = (c == 0 && kc < 2) ? preB[j * 2 + kc]
                                              : ldT(Ep, (tb + j) * 4 + kc, lane);
                #pragma unroll
                for (int i = 0; i < 4; ++i)
                    #pragma unroll
                    for (int j = 0; j < 4; ++j)
                        acc[i][j] = __builtin_amdgcn_mfma_f32_16x16x32_bf16(afr[kc][i], b[j], acc[i][j], 0, 0, 0);
            }
            float en[4];
            #pragma unroll
            for (int j = 0; j < 4; ++j) en[j] = enorms[(tb + j) * 16 + lrow];
            #pragma unroll
            for (int i = 0; i < 4; ++i)
                #pragma unroll
                for (int j = 0; j < 4; ++j)
                    #pragma unroll
                    for (int r = 0; r < 4; ++r) {
                        const float d2 = fmaf(-2.f, acc[i][j][r], en[j]);
                        const int s = i * 4 + r;
                        if (d2 < minv[s]) { minv[s] = d2; mini[s] = (tb + j) * 16 + lrow; }
                    }
        }
        #pragma unroll
        for (int off = 1; off < 16; off <<= 1) {
            #pragma unroll
            for (int s = 0; s < 16; ++s) {
                const float ov = __shfl_xor(minv[s], off, 64);
                const int   oi = __shfl_xor(mini[s], off, 64);
                if (ov < minv[s] || (ov == minv[s] && oi < mini[s])) { minv[s] = ov; mini[s] = oi; }
            }
        }
        if (lrow == 0) {
            #pragma unroll
            for (int i = 0; i < 4; ++i)
                #pragma unroll
                for (int r = 0; r < 4; ++r) {
                    red_val[wave][i * 16 + quad * 4 + r] = minv[i * 4 + r];
                    red_idx[wave][i * 16 + quad * 4 + r] = mini[i * 4 + r];
                }
        }
        // prefetch S6 first 2 kc-slices (j=2 x kc=2) — independent of the reductions
        #pragma unroll
        for (int j = 0; j < 2; ++j)
            #pragma unroll
            for (int kc = 0; kc < 2; ++kc)
                preB[j * 2 + kc] = ldT(Wd1p, (wave * 2 + j) * 4 + kc, lane);
    }
    __syncthreads();
    if (tid < MROWS) {
        float bv = red_val[0][tid]; int bi = red_idx[0][tid];
        #pragma unroll
        for (int w = 1; w < 8; ++w) {
            const float v = red_val[w][tid]; const int ii = red_idx[w][tid];
            if (v < bv || (v == bv && ii < bi)) { bv = v; bi = ii; }
        }
        qidx[tid] = bi;
    }
    __syncthreads();

    // ---------- S5: gather q -> buf cols 128..255 (enc in 0..127 untouched); vq += (enc-q)^2
    {
        const int row  = tid >> 3;             // 64 rows, 8 threads/row
        const int t    = tid & 7;
        const int kc   = t >> 1;
        const int half = t & 1;
        const int code = qidx[row];
        const int T    = (code >> 4) * 4 + kc;
        const u16* eb  = Ep + (T << 9) + (code & 15) * 8;
        #pragma unroll
        for (int h = 0; h < 2; ++h) {
            const int qd  = half * 2 + h;
            const u16x8 qv = *reinterpret_cast<const u16x8*>(eb + qd * 128);
            const int col = kc * 32 + qd * 8;
            const u16x8 ev = *reinterpret_cast<const u16x8*>(buf + row * SA + col);
            *reinterpret_cast<u16x8*>(buf + row * SA + 128 + col) = qv;
            #pragma unroll
            for (int e = 0; e < 8; ++e) {
                const float d = b2f(ev[e]) - b2f(qv[e]);
                vq_acc += d * d;
            }
        }
    }
    __syncthreads();

    // ---------- S6: d1 = relu(q @ Wd1^T + bd1): reads cols 128..255, writes 0..255
    {
        f32x4 acc[4][2];
        #pragma unroll
        for (int i = 0; i < 4; ++i)
            #pragma unroll
            for (int j = 0; j < 2; ++j) { f32x4 z = {0.f, 0.f, 0.f, 0.f}; acc[i][j] = z; }
        gemm_pre<2, 4, 2>(buf + 128, Wd1p, 4, wave * 2, preB, lane, lrow, kq, acc);
        // prefetch S7 first 4 kc-slices (j=2 x kc=4)
        #pragma unroll
        for (int j = 0; j < 2; ++j)
            #pragma unroll
            for (int kc = 0; kc < 4; ++kc)
                preB[j * 4 + kc] = ldT(Wd2p, (wave * 2 + j) * 8 + kc, lane);
        __syncthreads();                       // all waves done reading q
        epilogue_st<2>(buf, bd1, wave * 32, lrow, quad, true, acc);
    }
    __syncthreads();

    // ---------- S7: d2 = relu(d1 @ Wd2^T + bd2), in place   (NT=2, KC=8, PRE=4)
    {
        f32x4 acc[4][2];
        #pragma unroll
        for (int i = 0; i < 4; ++i)
            #pragma unroll
            for (int j = 0; j < 2; ++j) { f32x4 z = {0.f, 0.f, 0.f, 0.f}; acc[i][j] = z; }
        gemm_pre<2, 8, 4>(buf, Wd2p, 8, wave * 2, preB, lane, lrow, kq, acc);
        // prefetch S8 Wh fragments (waves 0..3 only)
        if (wave < 4) {
            #pragma unroll
            for (int kc = 0; kc < 8; ++kc) preB[kc] = ldT(Whp, kc, lane);
        }
        __syncthreads();                       // all waves done reading d1
        epilogue_st<2>(buf, bd2, wave * 32, lrow, quad, true, acc);
    }
    __syncthreads();

    // ---------- S8: recons = tanh(d2 @ Wh^T + bh); rec += (recons - action)^2 (fp32)
    if (wave < 4) {
        const int m0 = wave * 16;
        f32x4 acc = {0.f, 0.f, 0.f, 0.f};
        #pragma unroll
        for (int kc = 0; kc < 8; ++kc) {
            s16x8 a = ldb8(buf + (m0 + lrow) * SA + kc * 32 + kq);
            acc = __builtin_amdgcn_mfma_f32_16x16x32_bf16(a, preB[kc], acc, 0, 0, 0);
        }
        const float bias = bh[lrow];
        #pragma unroll
        for (int r = 0; r < 4; ++r) {
            const int row = m0 + quad * 4 + r;
            const float v = tanh_fast(acc[r] + bias);
            const float av = action[(base + row) * ADIM + lrow];
            const float d = v - av;
            rec_acc += d * d;
        }
    }

    // ---------- block reduction + atomics + last-block finalize
    #pragma unroll
    for (int off = 1; off < 64; off <<= 1) {
        vq_acc  += __shfl_xor(vq_acc,  off, 64);
        rec_acc += __shfl_xor(rec_acc, off, 64);
    }
    if (lane == 0) { wsum[wave] = rec_acc; wsum[8 + wave] = vq_acc; }
    __syncthreads();
    if (tid == 0) {
        float r = 0.f, v = 0.f;
        #pragma unroll
        for (int w = 0; w < 8; ++w) { r += wsum[w]; v += wsum[8 + w]; }
        atomicAdd(&sums[0], r);
        atomicAdd(&sums[1], v);
        __threadfence();
        const unsigned old = atomicAdd(counter, 1u);
        if (old == gridDim.x - 1) {
            const float s0 = atomicAdd(&sums[0], 0.f);
            const float s1 = atomicAdd(&sums[1], 0.f);
            const float recons_loss = s0 / (float)(BATCH * ADIM);
            const float vq_loss     = 1.25f * (s1 / (float)(BATCH * DDIM));
            out[0] = recons_loss + vq_loss;
        }
    }
}

extern "C" void kernel_launch(void* const* d_in, const int* in_sizes, int n_in,
                              void* d_out, int out_size, void* d_ws, size_t ws_size,
                              hipStream_t stream)
{
    const float* action = (const float*)d_in[0];
    const float* We1f = (const float*)d_in[1];
    const float* be1  = (const float*)d_in[2];
    const float* We2f = (const float*)d_in[3];
    const float* be2  = (const float*)d_in[4];
    const float* We3f = (const float*)d_in[5];
    const float* be3  = (const float*)d_in[6];
    const float* Ef   = (const float*)d_in[7];
    const float* Wd1f = (const float*)d_in[8];
    const float* bd1  = (const float*)d_in[9];
    const float* Wd2f = (const float*)d_in[10];
    const float* bd2  = (const float*)d_in[11];
    const float* Whf  = (const float*)d_in[12];
    const float* bh   = (const float*)d_in[13];

    float* ws = (float*)d_ws;          // [0]rec [1]vq [2]counter [3]pad [4..2052)enorms
    u16* wb = (u16*)(ws + 2052);       // packed bf16 area, 16B-aligned
    u16* Ep   = wb;                    // 262144
    u16* We1p = Ep   + KCODES * DDIM;  // 8192 (K padded to 32)
    u16* We2p = We1p + HDIM * 32;      // 65536
    u16* We3p = We2p + HDIM * HDIM;    // 32768
    u16* Wd1p = We3p + DDIM * HDIM;    // 32768
    u16* Wd2p = Wd1p + HDIM * DDIM;    // 65536
    u16* Whp  = Wd2p + HDIM * HDIM;    // 4096

    vqvae_prep<<<230, 256, 0, stream>>>(Ef, We1f, We2f, We3f, Wd1f, Wd2f, Whf,
                                        Ep, We1p, We2p, We3p, Wd1p, Wd2p, Whp, ws);
    ActionVQVAE_49452253446164_kernel<<<BATCH / MROWS, 512, 0, stream>>>(
        action, We1p, be1, We2p, be2, We3p, be3,
        Ep, ws + 4, Wd1p, bd1, Wd2p, bd2, Whp, bh,
        ws, (unsigned*)(ws + 2), (float*)d_out);
}